// Round 10
// baseline (298.621 us; speedup 1.0000x reference)
//
#include <hip/hip_runtime.h>
#include <hip/hip_bf16.h>
#include <cstdint>

typedef __bf16 bf16;
typedef __bf16 bf16x2 __attribute__((ext_vector_type(2)));
typedef __bf16 bf16x4 __attribute__((ext_vector_type(4)));
typedef __bf16 bf16x8 __attribute__((ext_vector_type(8)));
typedef float f32x4 __attribute__((ext_vector_type(4)));

#define B_ 2
#define S_ 2048
#define DM 1024
#define H_ 16
#define HD 64
#define NS (B_ * S_)    // 4096
#define QS 0.04508422f  // log2(e)/32 — folded into Wq^T and bq

// async global->LDS 16B: lane l's 16 bytes land at ldsbase + l*16.
__device__ __forceinline__ void gload_lds16(const bf16* g, bf16* l) {
  __builtin_amdgcn_global_load_lds((const __attribute__((address_space(1))) void*)g,
                                   (__attribute__((address_space(3))) void*)l,
                                   16, 0, 0);
}

// ---------------------------------------------------------------------------
// Transpose 4 fp32 1024x1024 weights -> bf16 W^T[n][k]; Wq^T scaled by QS.
__global__ __launch_bounds__(256) void transposeW_k(
    const float* __restrict__ w0, const float* __restrict__ w1,
    const float* __restrict__ w2, const float* __restrict__ w3,
    bf16* __restrict__ t0, bf16* __restrict__ t1,
    bf16* __restrict__ t2, bf16* __restrict__ t3) {
  const float* src = (blockIdx.z == 0) ? w0 : (blockIdx.z == 1) ? w1
                     : (blockIdx.z == 2) ? w2 : w3;
  bf16* dst = (blockIdx.z == 0) ? t0 : (blockIdx.z == 1) ? t1
              : (blockIdx.z == 2) ? t2 : t3;
  const float sc = (blockIdx.z == 0) ? QS : 1.0f;
  __shared__ float tile[32][33];
  const int tx = threadIdx.x, ty = threadIdx.y;  // 32 x 8
  const int x0 = blockIdx.x * 32, y0 = blockIdx.y * 32;
#pragma unroll
  for (int r = 0; r < 4; r++)
    tile[ty + r * 8][tx] = src[(size_t)(y0 + ty + r * 8) * DM + x0 + tx];
  __syncthreads();
#pragma unroll
  for (int r = 0; r < 4; r++)
    dst[(size_t)(x0 + ty + r * 8) * DM + y0 + tx] =
        (bf16)(tile[tx][ty + r * 8] * sc);
}

// ---------------------------------------------------------------------------
// C[M,N] = A[M,K] @ Bt[N,K]^T + bias.  128x128 tile, BK=32 (round-8 proven),
// 4 waves x (4x4) 16x16x32 bf16 MFMA.  Either operand may be fp32 in global
// (VGPR stage-convert w/ cross-iter prefetch) or bf16 (global_load_lds DMA).
// RBIAS: bias indexed by row (for the transposed V projection).
struct GArgs { const void* A; const void* Bt; const float* bias; void* C; float bscale; };
struct GArgs3 { GArgs g[3]; };

template <bool AF32, bool BF32, bool CF32, bool RBIAS>
__global__ __launch_bounds__(256) void gemm_k(GArgs3 args, int M, int N, int K) {
  const GArgs ga = args.g[blockIdx.z];
  __shared__ __align__(16) bf16 As[128 * 32];  // [m][k], stride 32
  __shared__ __align__(16) bf16 Bs[128 * 32];  // [n][k], stride 32
  const int tid = threadIdx.x;
  const int lane = tid & 63, w = tid >> 6;
  const int l15 = lane & 15, q = lane >> 4;
  const int wr = w >> 1, wc = w & 1;
  const int m0 = blockIdx.y * 128, n0 = blockIdx.x * 128;

  // chunk c (0..511): row c>>2, k-elems (c&3)*8..+7 at LDS elem c*8.
  const int c0 = w * 128 + lane, c1 = c0 + 64;
  const int r0 = c0 >> 2, r1 = c1 >> 2, koff = (c0 & 3) * 8;
  bf16* lA0 = As + (w * 2 + 0) * 512;
  bf16* lA1 = As + (w * 2 + 1) * 512;
  bf16* lB0 = Bs + (w * 2 + 0) * 512;
  bf16* lB1 = Bs + (w * 2 + 1) * 512;

  const bf16* Abf = (const bf16*)ga.A;
  const float* Afp = (const float*)ga.A;
  const bf16* Bbf = (const bf16*)ga.Bt;
  const float* Bfp = (const float*)ga.Bt;

  f32x4 apre[2][2], bpre[2][2];  // [chunk][lo/hi]
  if constexpr (AF32) {
    const float* p0 = Afp + (size_t)(m0 + r0) * K + koff;
    const float* p1 = Afp + (size_t)(m0 + r1) * K + koff;
    apre[0][0] = *(const f32x4*)p0; apre[0][1] = *(const f32x4*)(p0 + 4);
    apre[1][0] = *(const f32x4*)p1; apre[1][1] = *(const f32x4*)(p1 + 4);
  }
  if constexpr (BF32) {
    const float* p0 = Bfp + (size_t)(n0 + r0) * K + koff;
    const float* p1 = Bfp + (size_t)(n0 + r1) * K + koff;
    bpre[0][0] = *(const f32x4*)p0; bpre[0][1] = *(const f32x4*)(p0 + 4);
    bpre[1][0] = *(const f32x4*)p1; bpre[1][1] = *(const f32x4*)(p1 + 4);
  }

  f32x4 acc[4][4] = {};

  for (int k0 = 0; k0 < K; k0 += 32) {
    if constexpr (AF32) {
      bf16x8 v0, v1;
#pragma unroll
      for (int j = 0; j < 4; j++) {
        v0[j] = (bf16)apre[0][0][j]; v0[j + 4] = (bf16)apre[0][1][j];
        v1[j] = (bf16)apre[1][0][j]; v1[j + 4] = (bf16)apre[1][1][j];
      }
      *(bf16x8*)(lA0 + lane * 8) = v0;
      *(bf16x8*)(lA1 + lane * 8) = v1;
    } else {
      gload_lds16(Abf + (size_t)(m0 + r0) * K + koff + k0, lA0);
      gload_lds16(Abf + (size_t)(m0 + r1) * K + koff + k0, lA1);
    }
    if constexpr (BF32) {
      bf16x8 v0, v1;
#pragma unroll
      for (int j = 0; j < 4; j++) {
        v0[j] = (bf16)bpre[0][0][j]; v0[j + 4] = (bf16)bpre[0][1][j];
        v1[j] = (bf16)bpre[1][0][j]; v1[j + 4] = (bf16)bpre[1][1][j];
      }
      *(bf16x8*)(lB0 + lane * 8) = v0;
      *(bf16x8*)(lB1 + lane * 8) = v1;
    } else {
      gload_lds16(Bbf + (size_t)(n0 + r0) * K + koff + k0, lB0);
      gload_lds16(Bbf + (size_t)(n0 + r1) * K + koff + k0, lB1);
    }
    __syncthreads();  // drains async copies + LDS writes

    bf16x8 a[4], b[4];
#pragma unroll
    for (int mt = 0; mt < 4; mt++)
      a[mt] = *(const bf16x8*)(As + (wr * 64 + mt * 16 + l15) * 32 + q * 8);
#pragma unroll
    for (int nt = 0; nt < 4; nt++)
      b[nt] = *(const bf16x8*)(Bs + (wc * 64 + nt * 16 + l15) * 32 + q * 8);

    const int kn = (k0 + 32 < K) ? k0 + 32 : k0;
    if constexpr (AF32) {  // prefetch next chunk; overlaps MFMAs below
      const float* p0 = Afp + (size_t)(m0 + r0) * K + koff + kn;
      const float* p1 = Afp + (size_t)(m0 + r1) * K + koff + kn;
      apre[0][0] = *(const f32x4*)p0; apre[0][1] = *(const f32x4*)(p0 + 4);
      apre[1][0] = *(const f32x4*)p1; apre[1][1] = *(const f32x4*)(p1 + 4);
    }
    if constexpr (BF32) {
      const float* p0 = Bfp + (size_t)(n0 + r0) * K + koff + kn;
      const float* p1 = Bfp + (size_t)(n0 + r1) * K + koff + kn;
      bpre[0][0] = *(const f32x4*)p0; bpre[0][1] = *(const f32x4*)(p0 + 4);
      bpre[1][0] = *(const f32x4*)p1; bpre[1][1] = *(const f32x4*)(p1 + 4);
    }

#pragma unroll
    for (int mt = 0; mt < 4; mt++)
#pragma unroll
      for (int nt = 0; nt < 4; nt++)
        acc[mt][nt] = __builtin_amdgcn_mfma_f32_16x16x32_bf16(a[mt], b[nt],
                                                              acc[mt][nt], 0, 0, 0);
    __syncthreads();
  }

  // C/D layout: col = lane&15, row = (lane>>4)*4 + reg.
#pragma unroll
  for (int nt = 0; nt < 4; nt++) {
    const int col = n0 + wc * 64 + nt * 16 + l15;
    float bcol = 0.f;
    if constexpr (!RBIAS) bcol = ga.bias[col] * ga.bscale;
#pragma unroll
    for (int mt = 0; mt < 4; mt++) {
      const int row = m0 + wr * 64 + mt * 16 + q * 4;
      f32x4 brow;
      if constexpr (RBIAS) brow = *(const f32x4*)(ga.bias + row);
#pragma unroll
      for (int r = 0; r < 4; r++) {
        const float bv = RBIAS ? brow[r] * ga.bscale : bcol;
        const float val = acc[mt][nt][r] + bv;
        if constexpr (CF32)
          ((float*)ga.C)[(size_t)(row + r) * N + col] = val;
        else
          ((bf16*)ga.C)[(size_t)(row + r) * N + col] = (bf16)val;
      }
    }
  }
}

// ---------------------------------------------------------------------------
// Causal flash attention, no-max softmax (Q pre-scaled by log2e/32 upstream).
// Round-8 pipeline (K/V dbuf, ONE barrier/iter) + Q-fragments in registers
// (no Qs LDS -> 46.6 KB -> 3 blocks/CU) + V read from pre-transposed Vt
// (plain b128 staging, no scatter). Grid x: longest-first bit-reversed.
// Op aliases Qp: block reads only its own rows (at start) before writing them.
__global__ __launch_bounds__(256) void attn_k(const bf16* Qp, const bf16* Kp,
                                              const bf16* Vt, bf16* Op) {
  const int b = blockIdx.z, h = blockIdx.y;
  const int i = blockIdx.x;  // bit-reverse, longest tile first
  const int br = ((i & 1) << 4) | ((i & 2) << 2) | (i & 4) | ((i & 8) >> 2) |
                 ((i & 16) >> 4);
  const int i0 = (31 - br) * 64;
  const int tid = threadIdx.x;
  const int lane = tid & 63, w = tid >> 6;
  const int l15 = lane & 15, q = lane >> 4;

  __shared__ __align__(16) bf16 Ks[2][64][72];
  __shared__ __align__(16) bf16 Vts[2][64][72];  // [d][k]
  __shared__ __align__(16) bf16 Ps[4][16][76];   // stride 76: 2-way writes

  const size_t headoff = (size_t)b * S_ * DM + h * HD;
  const bf16* Kb = Kp + headoff;
  // Vt layout: [d_global = h*64+d][s_global = b*2048+s], row stride NS.
  const bf16* Vtb = Vt + (size_t)(h * HD) * NS + b * S_;

  const int kr0 = tid >> 3, kr1 = 32 + (tid >> 3), kcb = (tid & 7) * 8;

  // ---- Q fragments straight to registers (own rows only) ----
  const bf16* Qrow = Qp + headoff + (size_t)(i0 + w * 16 + l15) * DM;
  const bf16x8 aq0 = *(const bf16x8*)(Qrow + q * 8);
  const bf16x8 aq1 = *(const bf16x8*)(Qrow + 32 + q * 8);

  // ---- stage K/Vt for j0 = 0 into buf 0 ----
  *(bf16x8*)&Ks[0][kr0][kcb] = *(const bf16x8*)(Kb + (size_t)kr0 * DM + kcb);
  *(bf16x8*)&Ks[0][kr1][kcb] = *(const bf16x8*)(Kb + (size_t)kr1 * DM + kcb);
  *(bf16x8*)&Vts[0][kr0][kcb] = *(const bf16x8*)(Vtb + (size_t)kr0 * NS + kcb);
  *(bf16x8*)&Vts[0][kr1][kcb] = *(const bf16x8*)(Vtb + (size_t)kr1 * NS + kcb);
  __syncthreads();

  f32x4 oacc[4] = {};
  float rsum[4] = {0.f, 0.f, 0.f, 0.f};
  int buf = 0;

  for (int j0 = 0; j0 <= i0; j0 += 64, buf ^= 1) {
    // ---- prefetch next K/Vt tile into regs (4 b128 loads) ----
    const int jn = (j0 + 64 <= i0) ? j0 + 64 : 0;
    const bf16x8 kpre0 = *(const bf16x8*)(Kb + (size_t)(jn + kr0) * DM + kcb);
    const bf16x8 kpre1 = *(const bf16x8*)(Kb + (size_t)(jn + kr1) * DM + kcb);
    const bf16x8 vpre0 = *(const bf16x8*)(Vtb + (size_t)kr0 * NS + jn + kcb);
    const bf16x8 vpre1 = *(const bf16x8*)(Vtb + (size_t)kr1 * NS + jn + kcb);

    // ---- S = Q @ K^T (Q pre-scaled) ----
    f32x4 s[4] = {};
#pragma unroll
    for (int kk = 0; kk < 2; kk++) {
      const bf16x8 a = kk ? aq1 : aq0;
#pragma unroll
      for (int nt = 0; nt < 4; nt++) {
        bf16x8 bb = *(const bf16x8*)&Ks[buf][nt * 16 + l15][kk * 32 + q * 8];
        s[nt] = __builtin_amdgcn_mfma_f32_16x16x32_bf16(a, bb, s[nt], 0, 0, 0);
      }
    }

    // ---- p = exp2(s), causal mask on diagonal tile ----
    if (j0 == i0) {
      const int row = w * 16 + q * 4;
#pragma unroll
      for (int nt = 0; nt < 4; nt++) {
        const int col = nt * 16 + l15;
#pragma unroll
        for (int r = 0; r < 4; r++) {
          float p = (col <= row + r) ? __builtin_amdgcn_exp2f(s[nt][r]) : 0.f;
          rsum[r] += p;
          s[nt][r] = p;
        }
      }
    } else {
#pragma unroll
      for (int nt = 0; nt < 4; nt++)
#pragma unroll
        for (int r = 0; r < 4; r++) {
          const float p = __builtin_amdgcn_exp2f(s[nt][r]);
          rsum[r] += p;
          s[nt][r] = p;
        }
    }

    // ---- P -> LDS (C-layout -> A-layout), wave-local region ----
#pragma unroll
    for (int nt = 0; nt < 4; nt++)
#pragma unroll
      for (int r = 0; r < 4; r++)
        Ps[w][q * 4 + r][nt * 16 + l15] = (bf16)s[nt][r];
    asm volatile("s_waitcnt lgkmcnt(0)" ::: "memory");  // intra-wave LDS RAW

    // ---- O += P @ V ----
#pragma unroll
    for (int kk = 0; kk < 2; kk++) {
      bf16x4 alo = *(const bf16x4*)&Ps[w][l15][kk * 32 + q * 8];
      bf16x4 ahi = *(const bf16x4*)&Ps[w][l15][kk * 32 + q * 8 + 4];
      bf16x8 a;
#pragma unroll
      for (int j = 0; j < 4; j++) { a[j] = alo[j]; a[j + 4] = ahi[j]; }
#pragma unroll
      for (int nt = 0; nt < 4; nt++) {
        bf16x8 bb = *(const bf16x8*)&Vts[buf][nt * 16 + l15][kk * 32 + q * 8];
        oacc[nt] = __builtin_amdgcn_mfma_f32_16x16x32_bf16(a, bb, oacc[nt], 0, 0, 0);
      }
    }

    // ---- write prefetched tile into the other buffer ----
    *(bf16x8*)&Ks[buf ^ 1][kr0][kcb] = kpre0;
    *(bf16x8*)&Ks[buf ^ 1][kr1][kcb] = kpre1;
    *(bf16x8*)&Vts[buf ^ 1][kr0][kcb] = vpre0;
    *(bf16x8*)&Vts[buf ^ 1][kr1][kcb] = vpre1;
    __syncthreads();  // single barrier: buf^1 visible, buf reads done
  }

  // ---- epilogue: O / l ----
#pragma unroll
  for (int r = 0; r < 4; r++) {
    float t = rsum[r];
#pragma unroll
    for (int off = 1; off < 16; off <<= 1) t += __shfl_xor(t, off);
    rsum[r] = 1.0f / t;
  }
#pragma unroll
  for (int nt = 0; nt < 4; nt++) {
    const int d = nt * 16 + l15;
#pragma unroll
    for (int r = 0; r < 4; r++) {
      const int srow = i0 + w * 16 + q * 4 + r;
      Op[headoff + (size_t)srow * DM + d] = (bf16)(oacc[nt][r] * rsum[r]);
    }
  }
}

// ---------------------------------------------------------------------------
extern "C" void kernel_launch(void* const* d_in, const int* in_sizes, int n_in,
                              void* d_out, int out_size, void* d_ws, size_t ws_size,
                              hipStream_t stream) {
  const float* q_in = (const float*)d_in[0];
  const float* k_in = (const float*)d_in[1];
  const float* v_in = (const float*)d_in[2];
  // d_in[3] = causal mask, implemented analytically
  const float* Wq = (const float*)d_in[4];
  const float* bq = (const float*)d_in[5];
  const float* Wk = (const float*)d_in[6];
  const float* bk = (const float*)d_in[7];
  const float* Wv = (const float*)d_in[8];
  const float* bv = (const float*)d_in[9];
  const float* Wo = (const float*)d_in[10];
  const float* bo = (const float*)d_in[11];

  bf16* ws = (bf16*)d_ws;
  const size_t NQ = (size_t)B_ * S_ * DM;  // 4M elements
  bf16* Qp = ws;                           // attn writes in-place; then out-proj A
  bf16* Kp = ws + NQ;
  bf16* Vt = ws + 2 * NQ;                  // V^T [1024 d][4096 s]
  bf16* WqT = ws + 3 * NQ;                 // bf16 W^T (WqT pre-scaled by QS)
  bf16* WkT = WqT + (size_t)DM * DM;
  bf16* WvT = WkT + (size_t)DM * DM;
  bf16* WoT = WvT + (size_t)DM * DM;       // total ws: 32 MB (proven)

  transposeW_k<<<dim3(32, 32, 4), dim3(32, 8), 0, stream>>>(
      Wq, Wk, Wv, Wo, WqT, WkT, WvT, WoT);

  // Q/K projections: A = fp32 activations, Bt = bf16 W^T.
  GArgs3 gqk;
  gqk.g[0] = {q_in, WqT, bq, Qp, QS};
  gqk.g[1] = {k_in, WkT, bk, Kp, 1.0f};
  gqk.g[2] = gqk.g[0];
  gemm_k<true, false, false, false>
      <<<dim3(DM / 128, NS / 128, 2), 256, 0, stream>>>(gqk, NS, DM, DM);

  // V projection, transposed output: Vt[d][s] = sum_k WvT[d][k] * v_in[s][k].
  GArgs3 gv;
  gv.g[0] = {WvT, v_in, bv, Vt, 1.0f};
  gv.g[1] = gv.g[0];
  gv.g[2] = gv.g[0];
  gemm_k<false, true, false, true>
      <<<dim3(NS / 128, DM / 128, 1), 256, 0, stream>>>(gv, DM, NS, DM);

  attn_k<<<dim3(32, H_, B_), 256, 0, stream>>>(Qp, Kp, Vt, Qp);

  // Output projection -> fp32 d_out.
  GArgs3 gp;
  gp.g[0] = {Qp, WoT, bo, d_out, 1.0f};
  gp.g[1] = gp.g[0];
  gp.g[2] = gp.g[0];
  gemm_k<false, false, true, false>
      <<<dim3(DM / 128, NS / 128, 1), 256, 0, stream>>>(gp, NS, DM, DM);
}